// Round 11
// baseline (64.716 us; speedup 1.0000x reference)
//
#include <hip/hip_runtime.h>

#define B_ 4
#define T_ 4096
#define E_ 1024
#define H_ 64

typedef __attribute__((ext_vector_type(8))) short short8;   // 8 x bf16 (4 VGPRs)
typedef __attribute__((ext_vector_type(4))) float f32x4;    // MFMA accumulator

static __device__ __forceinline__ unsigned short f2bf(float f) {
    unsigned int u = __builtin_bit_cast(unsigned int, f);
    u += 0x7fffu + ((u >> 16) & 1u);   // round-to-nearest-even
    return (unsigned short)(u >> 16);
}
static __device__ __forceinline__ float bf2f(unsigned short h) {
    unsigned int u = ((unsigned int)h) << 16;
    return __builtin_bit_cast(float, u);
}
#if __has_builtin(__builtin_amdgcn_exp2f)
#define EXP2(x) __builtin_amdgcn_exp2f(x)
#else
#define EXP2(x) exp2f(x)
#endif

#define GLOBAL_AS __attribute__((address_space(1)))
#define LDS_AS    __attribute__((address_space(3)))

// ---------------------------------------------------------------------------
// Kernel 1: transpose W [1024][64] f32 -> Wt [3][64][1024] bf16
// ---------------------------------------------------------------------------
__global__ __launch_bounds__(256) void wt_transpose_kernel(
    const float* __restrict__ Wq, const float* __restrict__ Wk,
    const float* __restrict__ Wv, unsigned short* __restrict__ Wt)
{
    __shared__ float tile[64][65];
    const int mat = blockIdx.x >> 4;
    const int kt  = blockIdx.x & 15;
    const float* W = (mat == 0) ? Wq : ((mat == 1) ? Wk : Wv);
    const int tid = threadIdx.x;
    #pragma unroll
    for (int p = 0; p < 16; ++p) {
        int idx = p * 256 + tid;
        tile[idx >> 6][idx & 63] = W[(kt * 64 + (idx >> 6)) * 64 + (idx & 63)];
    }
    __syncthreads();
    #pragma unroll
    for (int p = 0; p < 16; ++p) {
        int idx = p * 256 + tid;
        int h = idx >> 6, kl = idx & 63;
        Wt[(mat * 64 + h) * E_ + kt * 64 + kl] = f2bf(tile[kl][h]);
    }
}

// ---------------------------------------------------------------------------
// Kernel 2: fused QKV projection, round 11: K-SPLIT for block concurrency.
// Cross-round model: per-CU global_load_lds ingest is ~7.7 B/cy with ONE
// block/CU, invariant to pipeline depth (r5/r7/r10); attn hits ~29 B/cy at
// 8 blocks/CU. Rate scales with independent blocks (separate barrier
// domains overlap each other's drains), not in-flight depth. r8's 2-block
// test was confounded (it duplicated Wt staging -> 1.5x volume).
// Now: grid 512 = 256 M-tiles x 2 K-halves; sibling blocks stage DIFFERENT
// K-ranges -> per-CU DMA volume unchanged, concurrency x2. LDS 80 KB ->
// exactly 2 blocks/CU. attn-style dbuf + __syncthreads (counted-vmcnt
// proved worthless at 1 block). Partials bf16 [2][16384][192]; merge sums.
// ---------------------------------------------------------------------------
__global__ __launch_bounds__(768, 6) void proj_kernel(
    const float* __restrict__ x, const unsigned short* __restrict__ Wt,
    unsigned short* __restrict__ Pp)
{
    __shared__ float          x_lds[2][4096];    // 2 x 16 KB (swizzled chunks)
    __shared__ unsigned short wt_lds[2][12288];  // 2 x 24 KB (swizzled chunks)
    const int tid  = threadIdx.x;
    const int wid  = tid >> 6, lane = tid & 63;
    const int g    = lane >> 4, c = lane & 15;
    const int mat  = wid >> 2;                   // 0=Q 1=K 2=V
    const int rg   = wid & 3;                    // 16-row group within block
    const int mtile = blockIdx.x >> 1;
    const int kh    = blockIdx.x & 1;            // K-half
    const int r0   = mtile * 64;
    const int k0   = kh * 512;

    // stage x[64 rows][kk..+64] (1024 16B chunks) + Wt[192 rows][kk..+64]
    // (1536 chunks). Involution chunk swizzle on the GLOBAL side; LDS linear.
    auto stage = [&](int buf, int kk) {
        {   // x: chunk idx = row*16+ch; LDS float offset = idx*4
            int row = tid >> 4, ch = tid & 15;
            int csw = ch ^ (row & 15);
            const float* src = x + (size_t)(r0 + row) * E_ + kk + csw * 4;
            __builtin_amdgcn_global_load_lds(
                (const GLOBAL_AS unsigned int*)src,
                (LDS_AS unsigned int*)&x_lds[buf][(tid & ~63) * 4], 16, 0, 0);
            if (tid < 256) {                     // waves 0-3: chunks 768..1023
                int idx2 = 768 + tid;
                int row2 = idx2 >> 4, ch2 = idx2 & 15;
                int csw2 = ch2 ^ (row2 & 15);
                const float* src2 = x + (size_t)(r0 + row2) * E_ + kk + csw2 * 4;
                __builtin_amdgcn_global_load_lds(
                    (const GLOBAL_AS unsigned int*)src2,
                    (LDS_AS unsigned int*)&x_lds[buf][(idx2 & ~63) * 4], 16, 0, 0);
            }
        }
        #pragma unroll
        for (int p = 0; p < 2; ++p) {            // Wt: 1536 chunks (8 per row)
            int idx = p * 768 + tid;
            int row = idx >> 3, ch = idx & 7;
            int csw = ch ^ (row & 7);
            const unsigned short* src = Wt + (size_t)row * E_ + kk + csw * 8;
            __builtin_amdgcn_global_load_lds(
                (const GLOBAL_AS unsigned int*)src,
                (LDS_AS unsigned int*)&wt_lds[buf][(idx & ~63) * 8], 16, 0, 0);
        }
    };

    f32x4 acc[4];
    #pragma unroll
    for (int n = 0; n < 4; ++n) acc[n] = 0.0f;

    const int xrowbase = (rg * 16 + c) * 64;
    const int wrowbase = (mat * 64 + c) * 64;
    auto computeStep = [&](int buf) {
        #pragma unroll
        for (int kc = 0; kc < 2; ++kc) {
            f32x4 xa = *(const f32x4*)&x_lds[buf][xrowbase + ((8 * kc + 2 * g)     ^ c) * 4];
            f32x4 xb = *(const f32x4*)&x_lds[buf][xrowbase + ((8 * kc + 2 * g + 1) ^ c) * 4];
            short8 a;
            #pragma unroll
            for (int j = 0; j < 4; ++j) {
                a[j]     = (short)f2bf(xa[j]);
                a[j + 4] = (short)f2bf(xb[j]);
            }
            #pragma unroll
            for (int n = 0; n < 4; ++n) {
                short8 b = *(const short8*)
                    &wt_lds[buf][wrowbase + n * 1024 + (((4 * kc + g) ^ (c & 7)) * 8)];
                acc[n] = __builtin_amdgcn_mfma_f32_16x16x32_bf16(a, b, acc[n], 0, 0, 0);
            }
        }
    };

    stage(0, k0);
    __syncthreads();
    for (int t = 0; t < 8; ++t) {
        const int buf = t & 1;
        if (t + 1 < 8) stage(buf ^ 1, k0 + (t + 1) * 64);
        computeStep(buf);
        __syncthreads();
    }

    // partial epilogue: Pp[kh][row][mat*64 + col] bf16 (raw sums; scale at merge)
    unsigned short* pp = Pp + ((size_t)kh * 16384 + r0) * 192;
    #pragma unroll
    for (int n = 0; n < 4; ++n)
        #pragma unroll
        for (int r = 0; r < 4; ++r)
            pp[(rg * 16 + 4 * g + r) * 192 + mat * 64 + n * 16 + c] = f2bf(acc[n][r]);
}

// ---------------------------------------------------------------------------
// Kernel 2b: merge K-split partials -> Qb (scaled), Kb, Vt (transposed).
// grid 1536 x 256; thread = (row, 8-col chunk of the 192-wide partial row).
// ---------------------------------------------------------------------------
__global__ __launch_bounds__(256) void qkv_merge_kernel(
    const unsigned short* __restrict__ Pp,
    unsigned short* __restrict__ Qb, unsigned short* __restrict__ Kb,
    unsigned short* __restrict__ Vt)
{
    const float QSCALE = 0.03125f * 1.44269504088896f;   // 1/sqrt(1024)*log2(e)
    const int idx   = blockIdx.x * 256 + threadIdx.x;    // [0, 393216)
    const int row   = idx / 24;
    const int chunk = idx - row * 24;

    short8 a = *(const short8*)&Pp[(size_t)row * 192 + chunk * 8];
    short8 b = *(const short8*)&Pp[((size_t)16384 + row) * 192 + chunk * 8];
    float s[8];
    #pragma unroll
    for (int j = 0; j < 8; ++j)
        s[j] = bf2f((unsigned short)a[j]) + bf2f((unsigned short)b[j]);

    if (chunk < 8) {
        short8 v;
        #pragma unroll
        for (int j = 0; j < 8; ++j) v[j] = (short)f2bf(s[j] * QSCALE);
        *(short8*)&Qb[(size_t)row * H_ + chunk * 8] = v;
    } else if (chunk < 16) {
        short8 v;
        #pragma unroll
        for (int j = 0; j < 8; ++j) v[j] = (short)f2bf(s[j]);
        *(short8*)&Kb[(size_t)row * H_ + (chunk - 8) * 8] = v;
    } else {
        const int col0 = (chunk - 16) * 8;
        const int bb   = row >> 12;
        const int rloc = row & (T_ - 1);
        #pragma unroll
        for (int j = 0; j < 8; ++j)
            Vt[((size_t)(bb * H_ + col0 + j)) * T_ + rloc] = f2bf(s[j]);
    }
}

// ---------------------------------------------------------------------------
// Kernel 3: split-K flash attention (round-5 version, unchanged).
// ---------------------------------------------------------------------------
__global__ __launch_bounds__(256, 3) void attn_split_kernel(
    const unsigned short* __restrict__ Qb, const unsigned short* __restrict__ Kb,
    const unsigned short* __restrict__ Vt, unsigned short* __restrict__ Po,
    float* __restrict__ Pl)
{
    __shared__ unsigned short K_lds[2][64][64];   // 16 KB (two 8 KB buffers)
    __shared__ unsigned short V_lds[2][64][64];   // 16 KB
    __shared__ unsigned short p_lds[4][16][72];   // 9 KB, per-wave P round-trip
    const int tid   = threadIdx.x;
    const int wid   = tid >> 6, lane = tid & 63;
    const int g     = lane >> 4, c = lane & 15;

    const int s     = blockIdx.x * 4 + wid;      // [0, 8192)
    const int batch = s >> 11;
    const int rem   = s & 2047;
    const int ch    = rem >> 8;                  // kv-chunk [0,8)
    const int qt    = rem & 255;                 // q-tile   [0,256)
    const int nkv   = (qt >> 2) + 1;             // total kv tiles for this qt
    if (ch * 8 >= nkv) return;                   // whole block exits together
    const int nt    = min(8, nkv - ch * 8);      // tiles in this chunk (same all waves)
    const int qbase = qt * 16;
    const int lastt = nkv - 1 - ch * 8;          // local idx of diagonal tile

    const int Mm = nkv - 1, aa = Mm >> 3, rr8 = Mm & 7;
    const int npart = (nkv + 7) >> 3;
    const int slot  = batch * 1152 + 4 * (4 * aa * (aa + 1) + rr8 * (aa + 1))
                    + (qt & 3) * npart + ch;

    const int rsub = lane >> 3;                  // staging: row-in-8
    const int csw  = (lane & 7) ^ rsub;          // involution chunk swizzle
    const int cs0 = (g ^ (c & 7)) * 8;           // read chunk offsets (lane-const)
    const int cs1 = ((g + 4) ^ (c & 7)) * 8;

    short8 aq0, aq1;                             // Q fragments (pre-scaled)
    {
        const unsigned short* qp = Qb + ((size_t)(batch * T_ + qbase + c)) * H_ + 8 * g;
        aq0 = *(const short8*)&qp[0];
        aq1 = *(const short8*)&qp[32];
    }

    short8 ones;                                 // bf16 1.0 fragment for l-MFMA
    #pragma unroll
    for (int j = 0; j < 8; ++j) ones[j] = (short)0x3F80;

    f32x4 o_acc[4];
    #pragma unroll
    for (int n = 0; n < 4; ++n) o_acc[n] = 0.0f;
    f32x4 l_acc = 0.0f;

    auto stage = [&](int buf, int gt) {
        const int key0 = gt * 64;
        #pragma unroll
        for (int j = 0; j < 2; ++j) {
            const int row = wid * 16 + j * 8;
            const unsigned short* gk = Kb
                + ((size_t)(batch * T_ + key0 + row + rsub)) * H_ + csw * 8;
            __builtin_amdgcn_global_load_lds(
                (const GLOBAL_AS unsigned int*)gk,
                (LDS_AS unsigned int*)&K_lds[buf][row][0], 16, 0, 0);
            const unsigned short* gv = Vt
                + ((size_t)(batch * H_ + row + rsub)) * T_ + key0 + csw * 8;
            __builtin_amdgcn_global_load_lds(
                (const GLOBAL_AS unsigned int*)gv,
                (LDS_AS unsigned int*)&V_lds[buf][row][0], 16, 0, 0);
        }
    };

    stage(0, ch * 8);
    __syncthreads();

    for (int t = 0; t < nt; ++t) {
        const int buf = t & 1;
        if (t + 1 < nt) stage(buf ^ 1, ch * 8 + t + 1);

        // ---- S = Q K^T (K frags from LDS, swizzled chunks) ----
        f32x4 sA[4];
        #pragma unroll
        for (int n = 0; n < 4; ++n) sA[n] = 0.0f;
        #pragma unroll
        for (int n = 0; n < 4; ++n) {
            short8 bk0 = *(const short8*)&K_lds[buf][n * 16 + c][cs0];
            short8 bk1 = *(const short8*)&K_lds[buf][n * 16 + c][cs1];
            sA[n] = __builtin_amdgcn_mfma_f32_16x16x32_bf16(aq0, bk0, sA[n], 0, 0, 0);
            sA[n] = __builtin_amdgcn_mfma_f32_16x16x32_bf16(aq1, bk1, sA[n], 0, 0, 0);
        }

        // ---- p = exp2(s); mask only the diagonal tile ----
        float pv[4][4];
        #pragma unroll
        for (int n = 0; n < 4; ++n)
            #pragma unroll
            for (int r = 0; r < 4; ++r)
                pv[n][r] = EXP2(sA[n][r]);
        if (t == lastt) {                        // wave-uniform branch
            const int d = (ch * 8 + t) * 64 + c - qbase - 4 * g;
            #pragma unroll
            for (int n = 0; n < 4; ++n)
                #pragma unroll
                for (int r = 0; r < 4; ++r)
                    if (d + 16 * n > r) pv[n][r] = 0.0f;
        }

        // ---- P: D-layout -> A-frag layout via per-wave LDS ----
        #pragma unroll
        for (int n = 0; n < 4; ++n)
            #pragma unroll
            for (int r = 0; r < 4; ++r)
                p_lds[wid][4 * g + r][n * 16 + c] = f2bf(pv[n][r]);
        short8 pa0 = *(const short8*)&p_lds[wid][c][8 * g];
        short8 pa1 = *(const short8*)&p_lds[wid][c][32 + 8 * g];

        // ---- l += P * 1 ----
        l_acc = __builtin_amdgcn_mfma_f32_16x16x32_bf16(pa0, ones, l_acc, 0, 0, 0);
        l_acc = __builtin_amdgcn_mfma_f32_16x16x32_bf16(pa1, ones, l_acc, 0, 0, 0);

        // ---- O += P V (V frags from LDS, swizzled chunks) ----
        #pragma unroll
        for (int n = 0; n < 4; ++n) {
            short8 bv0 = *(const short8*)&V_lds[buf][n * 16 + c][cs0];
            short8 bv1 = *(const short8*)&V_lds[buf][n * 16 + c][cs1];
            o_acc[n] = __builtin_amdgcn_mfma_f32_16x16x32_bf16(pa0, bv0, o_acc[n], 0, 0, 0);
            o_acc[n] = __builtin_amdgcn_mfma_f32_16x16x32_bf16(pa1, bv1, o_acc[n], 0, 0, 0);
        }

        __syncthreads();
    }

    unsigned short* po = Po + (size_t)slot * 1024;
    #pragma unroll
    for (int n = 0; n < 4; ++n)
        #pragma unroll
        for (int r = 0; r < 4; ++r)
            po[(4 * g + r) * 64 + n * 16 + c] = f2bf(o_acc[n][r]);
    if (c == 0) {
        #pragma unroll
        for (int r = 0; r < 4; ++r)
            Pl[slot * 16 + 4 * g + r] = l_acc[r];
    }
}

// ---------------------------------------------------------------------------
// Kernel 4: merge attention partials — plain sums. One wave per q-tile.
// ---------------------------------------------------------------------------
__global__ __launch_bounds__(256) void attn_merge_kernel(
    const unsigned short* __restrict__ Po, const float* __restrict__ Pl,
    float* __restrict__ out)
{
    const int tid  = threadIdx.x;
    const int wid  = tid >> 6, lane = tid & 63;
    const int gi   = blockIdx.x * 4 + wid;       // [0, 1024)
    const int batch = gi >> 8, qt = gi & 255;
    const int nkv  = (qt >> 2) + 1;
    const int npart = (nkv + 7) >> 3;
    const int Mm = nkv - 1, aa = Mm >> 3, rr8 = Mm & 7;
    const int slot0 = batch * 1152 + 4 * (4 * aa * (aa + 1) + rr8 * (aa + 1))
                    + (qt & 3) * npart;

    const int row = lane & 15, seg = lane >> 4;

    float lacc = 0.0f, o[16];
    #pragma unroll
    for (int k = 0; k < 16; ++k) o[k] = 0.0f;

    for (int i = 0; i < npart; ++i) {
        lacc += Pl[(slot0 + i) * 16 + row];
        const unsigned short* pp = Po + (size_t)(slot0 + i) * 1024 + row * 64 + seg * 16;
        short8 v0 = *(const short8*)&pp[0];
        short8 v1 = *(const short8*)&pp[8];
        #pragma unroll
        for (int k = 0; k < 8; ++k) {
            o[k]     += bf2f((unsigned short)v0[k]);
            o[8 + k] += bf2f((unsigned short)v1[k]);
        }
    }

    const float inv = 1.0f / lacc;
    float* op = out + ((size_t)(batch * T_ + qt * 16 + row)) * H_ + seg * 16;
    #pragma unroll
    for (int k = 0; k < 16; ++k) op[k] = o[k] * inv;
}

// ---------------------------------------------------------------------------
extern "C" void kernel_launch(void* const* d_in, const int* in_sizes, int n_in,
                              void* d_out, int out_size, void* d_ws, size_t ws_size,
                              hipStream_t stream)
{
    const float* x  = (const float*)d_in[0];
    const float* Wk = (const float*)d_in[1];
    const float* Wq = (const float*)d_in[2];
    const float* Wv = (const float*)d_in[3];
    float* out = (float*)d_out;

    // workspace layout:
    //   Wt  [3*64*1024] bf16            384 KB
    //   Qb/Kb [B*T*H] bf16            2+2 MB
    //   Vt  [B*H*T] bf16                  2 MB
    //   U: union (disjoint lifetimes):
    //     Pp [2][16384][192] bf16      12.6 MB  (proj partials; dead after merge)
    //     Po [4608][16][64] bf16 + Pl   9.7 MB  (attn partials; live after)
    //   total ~19 MB
    unsigned short* Wt = (unsigned short*)d_ws;
    unsigned short* Qb = Wt + 3 * 64 * 1024;
    unsigned short* Kb = Qb + (size_t)B_ * T_ * H_;
    unsigned short* Vt = Kb + (size_t)B_ * T_ * H_;
    unsigned short* U  = Vt + (size_t)B_ * T_ * H_;
    unsigned short* Pp = U;                       // proj partials
    unsigned short* Po = U;                       // attn partials (aliases Pp)
    float* Pl = (float*)(Po + (size_t)4608 * 1024);

    hipLaunchKernelGGL(wt_transpose_kernel, dim3(48), dim3(256), 0, stream, Wq, Wk, Wv, Wt);
    hipLaunchKernelGGL(proj_kernel, dim3(512), dim3(768), 0, stream, x, Wt, Pp);
    hipLaunchKernelGGL(qkv_merge_kernel, dim3(1536), dim3(256), 0, stream, Pp, Qb, Kb, Vt);
    hipLaunchKernelGGL(attn_split_kernel, dim3(2048), dim3(256), 0, stream, Qb, Kb, Vt, Po, Pl);
    hipLaunchKernelGGL(attn_merge_kernel, dim3(256), dim3(256), 0, stream, Po, Pl, out);
}